// Round 5
// baseline (228.093 us; speedup 1.0000x reference)
//
#include <hip/hip_runtime.h>
#include <math.h>

// Problem constants
#define B_   32
#define P_   8
#define K_   17
#define H_   192
#define W_   192
#define HW_  (H_*W_)              // 36864
#define NBK  (B_*K_)              // 544

// block families (one heterogeneous launch, 256 threads each)
#define STREAM_PER_B 153          // 153 * 4096 = 626688 = K*H*W
#define STREAM_BLKS  (B_*STREAM_PER_B)       // 4896
#define STAMP_BLKS   (B_*K_*P_)              // 4352
#define TSQ_BLKS     NBK                     // 544
#define BCE_BLKS     96                      // 96*12288 = B*H*W
#define STAMP_BASE   STREAM_BLKS             // 4896
#define TSQ_BASE     (STAMP_BASE+STAMP_BLKS) // 9248
#define BCE_BASE     (TSQ_BASE+TSQ_BLKS)     // 9792
#define TOTAL_BLKS   (BCE_BASE+BCE_BLKS)     // 9888

#define RADIUS 18                 // exp(-18^2/18)=exp(-18)~1.5e-8: negligible
#define WIN    (2*RADIUS+1)       // 37

// ws layout (floats)
#define WS_STREAM 0               // 4896*4: (S2, Zu, Zv, A) per stream block
#define WS_STAMP  20480           // 4352: cross-term partial per (b,k,p)
#define WS_TSQ    25088           // 544:  sum(t^2) per (b,k)
#define WS_BCE    25728           // 96

__device__ inline float wave_red_sum(float v) {
    for (int o = 32; o; o >>= 1) v += __shfl_xor(v, o, 64);
    return v;
}

// =====================================================================
// mega kernel, 256 threads/block. LDS kept tiny (<0.5 KB) on ALL paths:
// r2/r3/r4 pose kernels with 7-13 KB LDS tables were all pinned at
// ~80 us with OccupancyPercent ~21-27% despite VGPR/LDS limits allowing
// 32 waves/CU; r1's 512B-LDS streaming kernel reached 53%. This round
// removes LDS tables from the hot path via
//   MSE = sum(pred^2) - 2*sum(pred*t) + sum(t^2)
// with sum(pred^2)+KL fully streaming, sum(pred*t) as 37x37 compact
// stamps, and sum(t^2) in closed form (separable 1-D Gaussian dots).
// =====================================================================
__global__ void __launch_bounds__(256) main_kernel(
        const float* __restrict__ s_pose, const float* __restrict__ t_pose,
        const float* __restrict__ kps,    const int* __restrict__ vis,
        const float* __restrict__ s_seg,  const float* __restrict__ mask,
        float* __restrict__ ws) {
    __shared__ float sred[4][4];
    __shared__ float gx_s[WIN + 3], gy_s[WIN + 3];

    const int blk = blockIdx.x;
    const int tid = threadIdx.x;
    const float inv18 = 1.0f / 18.0f;

    if (blk < STREAM_BLKS) {
        // ---------- streaming: KL sums + sum(pred^2), no tables ----------
        int b = blk / STREAM_PER_B;
        int r = blk - b*STREAM_PER_B;
        const float4* s4 = (const float4*)s_pose + (size_t)b*(STREAM_PER_B*1024) + (size_t)r*1024;
        const float4* t4 = (const float4*)t_pose + (size_t)b*(STREAM_PER_B*1024) + (size_t)r*1024;
        float S2 = 0.f, Zu = 0.f, Zv = 0.f, A = 0.f;
#pragma unroll
        for (int j = 0; j < 4; j++) {
            float4 sv = s4[j*256 + tid];
            float4 tv = t4[j*256 + tid];
            S2 += sv.x*sv.x + sv.y*sv.y + sv.z*sv.z + sv.w*sv.w;
            float u0 = tv.x*0.5f, v0 = sv.x*0.5f;
            float u1 = tv.y*0.5f, v1 = sv.y*0.5f;
            float u2 = tv.z*0.5f, v2 = sv.z*0.5f;
            float u3 = tv.w*0.5f, v3 = sv.w*0.5f;
            float e0 = __expf(u0), e1 = __expf(u1), e2 = __expf(u2), e3 = __expf(u3);
            Zu += (e0 + e1) + (e2 + e3);
            A  += (e0*(u0-v0) + e1*(u1-v1)) + (e2*(u2-v2) + e3*(u3-v3));
            Zv += (__expf(v0) + __expf(v1)) + (__expf(v2) + __expf(v3));
        }
        S2 = wave_red_sum(S2);
        Zu = wave_red_sum(Zu);
        Zv = wave_red_sum(Zv);
        A  = wave_red_sum(A);
        int w = tid >> 6;
        if ((tid & 63) == 0) {
            sred[w][0] = S2; sred[w][1] = Zu; sred[w][2] = Zv; sred[w][3] = A;
        }
        __syncthreads();
        if (tid == 0) {
            float* o = ws + WS_STREAM + (size_t)blk * 4;
            o[0] = sred[0][0] + sred[1][0] + sred[2][0] + sred[3][0];
            o[1] = sred[0][1] + sred[1][1] + sred[2][1] + sred[3][1];
            o[2] = sred[0][2] + sred[1][2] + sred[2][2] + sred[3][2];
            o[3] = sred[0][3] + sred[1][3] + sred[2][3] + sred[3][3];
        }
        return;
    }

    if (blk < TSQ_BASE) {
        // ---------- stamp: cross = sum_{37x37 window} pred*gx*gy ----------
        int sb  = blk - STAMP_BASE;
        int b   = sb / (K_*P_);
        int rem = sb - b*(K_*P_);
        int k   = rem / P_;
        int p   = rem - k*P_;
        // wave-uniform scalar loads (all lanes same address -> broadcast)
        float kx = kps[((b*P_ + p)*K_ + k)*2 + 0];
        float ky = kps[((b*P_ + p)*K_ + k)*2 + 1];
        int   vv = vis[(b*P_ + p)*K_ + k];
        float fx = floorf(kx * (float)(W_-1));   // row center (reference quirk)
        float fy = floorf(ky * (float)(H_-1));   // col center
        bool ok = (vv > 0) && (fx >= 0.f) && (fx < (float)W_) && (fy >= 0.f) && (fy < (float)H_);
        if (!ok) { if (tid == 0) ws[WS_STAMP + sb] = 0.f; return; }
        int X0 = max(0, (int)fx - RADIUS), X1 = min(H_-1, (int)fx + RADIUS);
        int Y0 = max(0, (int)fy - RADIUS), Y1 = min(W_-1, (int)fy + RADIUS);
        int nr = X1 - X0 + 1, nc = Y1 - Y0 + 1;
        if (tid < nr) {
            float d = (float)(X0 + tid) - fx;
            gx_s[tid] = __expf(-d*d*inv18);
        } else if (tid >= 64 && tid - 64 < nc) {
            float d = (float)(Y0 + tid - 64) - fy;
            gy_s[tid - 64] = __expf(-d*d*inv18);
        }
        __syncthreads();
        const float* pb = s_pose + (size_t)(b*K_ + k) * HW_;
        float acc = 0.f;
        int lim = nr << 6;                 // rows x 64 lanes (cols padded)
        for (int e = tid; e < lim; e += 256) {
            int row = e >> 6, col = e & 63;
            if (col < nc)
                acc += pb[(X0 + row)*W_ + (Y0 + col)] * gx_s[row] * gy_s[col];
        }
        acc = wave_red_sum(acc);
        if ((tid & 63) == 0) sred[0][tid >> 6] = acc;
        __syncthreads();
        if (tid == 0)
            ws[WS_STAMP + sb] = sred[0][0] + sred[0][1] + sred[0][2] + sred[0][3];
        return;
    }

    if (blk < BCE_BASE) {
        // ---------- tsq: sum(t^2) closed form via separable 1-D dots ----
        // sum_px t^2 = sum_{p,q} vld_p vld_q (sum_i gxp gxq)(sum_j gyp gyq)
        int sb = blk - TSQ_BASE;
        int b = sb / K_, k = sb - b*K_;
        int pq = tid >> 2, p = pq >> 3, q = pq & 7, ln = tid & 3;
        float kxp = kps[((b*P_ + p)*K_ + k)*2 + 0];
        float kyp = kps[((b*P_ + p)*K_ + k)*2 + 1];
        float kxq = kps[((b*P_ + q)*K_ + k)*2 + 0];
        float kyq = kps[((b*P_ + q)*K_ + k)*2 + 1];
        int vp = vis[(b*P_ + p)*K_ + k];
        int vq = vis[(b*P_ + q)*K_ + k];
        float axp = floorf(kxp * 191.f), ayp = floorf(kyp * 191.f);
        float axq = floorf(kxq * 191.f), ayq = floorf(kyq * 191.f);
        bool okp = (vp > 0) && axp >= 0.f && axp < 192.f && ayp >= 0.f && ayp < 192.f;
        bool okq = (vq > 0) && axq >= 0.f && axq < 192.f && ayq >= 0.f && ayq < 192.f;
        float sx = 0.f, sy = 0.f;
        int i0 = ln * 48;
        for (int i = i0; i < i0 + 48; i++) {
            float da = (float)i - axp, db = (float)i - axq;
            sx += __expf(-(da*da + db*db)*inv18);
            float ea = (float)i - ayp, eb = (float)i - ayq;
            sy += __expf(-(ea*ea + eb*eb)*inv18);
        }
        sx += __shfl_xor(sx, 1, 64); sy += __shfl_xor(sy, 1, 64);
        sx += __shfl_xor(sx, 2, 64); sy += __shfl_xor(sy, 2, 64);
        float val = (ln == 0 && okp && okq) ? sx * sy : 0.f;
        val = wave_red_sum(val);
        if ((tid & 63) == 0) sred[0][tid >> 6] = val;
        __syncthreads();
        if (tid == 0)
            ws[WS_TSQ + sb] = sred[0][0] + sred[0][1] + sred[0][2] + sred[0][3];
        return;
    }

    // ---------------- BCE partials ----------------
    {
        int bidx = blk - BCE_BASE;
        const float4* x4 = (const float4*)s_seg;
        const float4* m4 = (const float4*)mask;
        size_t base = (size_t)bidx * 3072 + tid;   // 3072 float4 per block
        float acc = 0.f;
#pragma unroll 4
        for (int j = 0; j < 12; j++) {
            float4 xv = x4[base + j*256];
            float4 tv = m4[base + j*256];
            acc += fmaxf(xv.x, 0.f) - xv.x*tv.x + log1pf(__expf(-fabsf(xv.x)));
            acc += fmaxf(xv.y, 0.f) - xv.y*tv.y + log1pf(__expf(-fabsf(xv.y)));
            acc += fmaxf(xv.z, 0.f) - xv.z*tv.z + log1pf(__expf(-fabsf(xv.z)));
            acc += fmaxf(xv.w, 0.f) - xv.w*tv.w + log1pf(__expf(-fabsf(xv.w)));
        }
        acc = wave_red_sum(acc);
        if ((tid & 63) == 0) sred[0][tid >> 6] = acc;
        __syncthreads();
        if (tid == 0)
            ws[WS_BCE + bidx] = sred[0][0] + sred[0][1] + sred[0][2] + sred[0][3];
    }
}

// =====================================================================
// finalize: 1 block x 256 threads; 8 threads per batch row b.
//   mse_b = S2_b - 2*cross_b + tsq_b ;  KL_b = A/Zu + log(Zv) - log(Zu)
// =====================================================================
__global__ void __launch_bounds__(256) finalize_kernel(
        const float* __restrict__ ws, const int* __restrict__ vis,
        float* __restrict__ out) {
    __shared__ float rS2[B_][8], rZu[B_][8], rZv[B_][8], rA[B_][8];
    __shared__ float rCr[B_][8], rTq[B_][8];
    __shared__ int   rVs[B_][8];
    __shared__ float skl[B_], skp[B_];
    __shared__ float bw[4];
    int tid = threadIdx.x;
    int b = tid >> 3, s = tid & 7;

    float S2 = 0.f, Zu = 0.f, Zv = 0.f, A = 0.f, cr = 0.f, tq = 0.f;
    for (int j = s; j < STREAM_PER_B; j += 8) {
        const float* p = ws + WS_STREAM + (size_t)(b*STREAM_PER_B + j) * 4;
        S2 += p[0]; Zu += p[1]; Zv += p[2]; A += p[3];
    }
    for (int j = s; j < K_*P_; j += 8) cr += ws[WS_STAMP + b*(K_*P_) + j];
    for (int j = s; j < K_;    j += 8) tq += ws[WS_TSQ + b*K_ + j];
    int vs = 0;
    for (int m = s; m < P_*K_; m += 8) vs += vis[b*(P_*K_) + m];
    rS2[b][s] = S2; rZu[b][s] = Zu; rZv[b][s] = Zv; rA[b][s] = A;
    rCr[b][s] = cr; rTq[b][s] = tq; rVs[b][s] = vs;

    float bce = (tid < BCE_BLKS) ? ws[WS_BCE + tid] : 0.f;
    bce = wave_red_sum(bce);
    if ((tid & 63) == 0) bw[tid >> 6] = bce;
    __syncthreads();

    if (tid < B_) {
        float tS2=0.f, tZu=0.f, tZv=0.f, tA=0.f, tCr=0.f, tTq=0.f; int tVs=0;
#pragma unroll
        for (int q2 = 0; q2 < 8; q2++) {
            tS2 += rS2[tid][q2]; tZu += rZu[tid][q2]; tZv += rZv[tid][q2];
            tA  += rA[tid][q2];  tCr += rCr[tid][q2]; tTq += rTq[tid][q2];
            tVs += rVs[tid][q2];
        }
        float mse = tS2 - 2.f*tCr + tTq;
        skl[tid] = tA/tZu + (logf(tZv) - logf(tZu));
        skp[tid] = mse / ((float)tVs + 1e-6f);
    }
    __syncthreads();

    if (tid == 0) {
        float kl = 0.f, kpv = 0.f;
        for (int i = 0; i < B_; i++) { kl += skl[i]; kpv += skp[i]; }
        float bsum = bw[0] + bw[1] + bw[2] + bw[3];
        float pose_distill = 4.0f * kl / (float)B_;   // TEMP^2=4, batchmean
        float task_seg  = bsum / (float)(B_ * HW_);
        float task_pose = kpv / (float)B_;
        // seg_distill == 0 exactly (softmax over a size-1 channel axis)
        out[0] = 0.5f * pose_distill + 0.5f * (task_seg + task_pose);
    }
}

extern "C" void kernel_launch(void* const* d_in, const int* in_sizes, int n_in,
                              void* d_out, int out_size, void* d_ws, size_t ws_size,
                              hipStream_t stream) {
    const float* s_seg  = (const float*)d_in[0];
    const float* s_pose = (const float*)d_in[1];
    // d_in[2] (t_seg_logits) unused: seg_distill == 0 exactly
    const float* t_pose = (const float*)d_in[3];
    const float* mask   = (const float*)d_in[4];
    const float* kps    = (const float*)d_in[5];
    const int*   vis    = (const int*)d_in[6];
    float* out = (float*)d_out;
    float* ws  = (float*)d_ws;

    main_kernel<<<TOTAL_BLKS, 256, 0, stream>>>(s_pose, t_pose, kps, vis,
                                                s_seg, mask, ws);
    finalize_kernel<<<1, 256, 0, stream>>>(ws, vis, out);
}

// Round 6
// 215.980 us; speedup vs baseline: 1.0561x; 1.0561x over previous
//
#include <hip/hip_runtime.h>
#include <math.h>

// Problem constants
#define B_   32
#define P_   8
#define K_   17
#define H_   192
#define W_   192
#define HW_  (H_*W_)              // 36864
#define PB4   156672              // K*H*W/4 float4 per batch row
#define NBLKS 2048                // 8 blocks/CU persistent
#define PER_B_BLKS 64             // blocks per batch row
#define CHUNK 16384               // 64 blocks * 256 threads (float4 stride)
#define FULL_IT 9                 // 9*16384 = 147456 of 156672
#define REM4  9216                // remainder float4 per b
#define BCE4  294912              // B*H*W/4

#define STAMP_UNITS (B_*K_*P_)    // 4352
#define TSQ_UNITS   (B_*K_)       // 544
#define RADIUS 18                 // exp(-18) ~ 1.5e-8: negligible tail

// ws layout (floats)
#define WS_BLK   0                // 2048*8: (S2,Zu,Zv,A,bce) per block
#define WS_STAMP 16384            // 4352: cross partial per (b,k,p)
#define WS_TSQ   20736            // 544: sum(t^2) per (b,k)

__device__ inline float wave_red_sum(float v) {
    for (int o = 32; o; o >>= 1) v += __shfl_xor(v, o, 64);
    return v;
}

__device__ inline void kl_elem(float sv, float tv,
        float& S2, float& Zu, float& Zv, float& A) {
    S2 += sv*sv;
    float u = tv*0.5f, v = sv*0.5f;
    float eu = __expf(u);
    Zu += eu;
    A  += eu*(u - v);
    Zv += __expf(v);
}

// =====================================================================
// Persistent copy-bench-shaped kernel: 2048 blocks x 256 thr (8/CU).
// Phase 1: grid-stride KL+sum(pred^2) stream over one batch row per
//          block-group (9 unconditional float4-pair iters + remainder),
//          unroll-3 -> 6 loads in flight, NO mid-phase reductions.
// Phase 2: BCE (one conditional float4-pair per thread).
//          -> ONE 5-value block reduction for phases 1-2.
// Phase 3: cross-term 37x37 stamps, grid-stride (2-3 per block).
// Phase 4: sum(t^2) closed form (blocks 0..543).
// MSE = S2 - 2*cross + tsq (r5-verified algebra, absmax 0).
// =====================================================================
__global__ void __launch_bounds__(256) main_kernel(
        const float* __restrict__ s_pose, const float* __restrict__ t_pose,
        const float* __restrict__ kps,    const int* __restrict__ vis,
        const float* __restrict__ s_seg,  const float* __restrict__ mask,
        float* __restrict__ ws) {
    __shared__ float sred[4][5];
    __shared__ float gx_s[40], gy_s[40];

    const int blk = blockIdx.x;
    const int tid = threadIdx.x;
    const float inv18 = 1.0f / 18.0f;

    // ---------------- phase 1: pose stream (b-pinned) ----------------
    const int b  = blk >> 6;                     // 64 blocks per b
    const int lg = ((blk & 63) << 8) | tid;      // 0..16383 within b
    const float4* s4 = (const float4*)s_pose + (size_t)b*PB4 + lg;
    const float4* t4 = (const float4*)t_pose + (size_t)b*PB4 + lg;

    float S2 = 0.f, Zu = 0.f, Zv = 0.f, A = 0.f;
#pragma unroll 3
    for (int j = 0; j < FULL_IT; j++) {
        float4 sv = s4[(size_t)j*CHUNK];
        float4 tv = t4[(size_t)j*CHUNK];
        kl_elem(sv.x, tv.x, S2, Zu, Zv, A);
        kl_elem(sv.y, tv.y, S2, Zu, Zv, A);
        kl_elem(sv.z, tv.z, S2, Zu, Zv, A);
        kl_elem(sv.w, tv.w, S2, Zu, Zv, A);
    }
    if (lg < REM4) {
        float4 sv = s4[(size_t)FULL_IT*CHUNK];
        float4 tv = t4[(size_t)FULL_IT*CHUNK];
        kl_elem(sv.x, tv.x, S2, Zu, Zv, A);
        kl_elem(sv.y, tv.y, S2, Zu, Zv, A);
        kl_elem(sv.z, tv.z, S2, Zu, Zv, A);
        kl_elem(sv.w, tv.w, S2, Zu, Zv, A);
    }

    // ---------------- phase 2: BCE (one iter per thread) ----------------
    float bce = 0.f;
    {
        int gid = (blk << 8) | tid;
        if (gid < BCE4) {
            float4 xv = ((const float4*)s_seg)[gid];
            float4 mv = ((const float4*)mask)[gid];
            bce += fmaxf(xv.x, 0.f) - xv.x*mv.x + log1pf(__expf(-fabsf(xv.x)));
            bce += fmaxf(xv.y, 0.f) - xv.y*mv.y + log1pf(__expf(-fabsf(xv.y)));
            bce += fmaxf(xv.z, 0.f) - xv.z*mv.z + log1pf(__expf(-fabsf(xv.z)));
            bce += fmaxf(xv.w, 0.f) - xv.w*mv.w + log1pf(__expf(-fabsf(xv.w)));
        }
    }

    // ---------------- single 5-value block reduction ----------------
    S2  = wave_red_sum(S2);
    Zu  = wave_red_sum(Zu);
    Zv  = wave_red_sum(Zv);
    A   = wave_red_sum(A);
    bce = wave_red_sum(bce);
    {
        int w = tid >> 6;
        if ((tid & 63) == 0) {
            sred[w][0] = S2; sred[w][1] = Zu; sred[w][2] = Zv;
            sred[w][3] = A;  sred[w][4] = bce;
        }
    }
    __syncthreads();
    if (tid == 0) {
        float* o = ws + WS_BLK + (size_t)blk * 8;
#pragma unroll
        for (int c = 0; c < 5; c++)
            o[c] = sred[0][c] + sred[1][c] + sred[2][c] + sred[3][c];
    }

    // ---------------- phase 3: cross-term stamps ----------------
    for (int u = blk; u < STAMP_UNITS; u += NBLKS) {
        __syncthreads();   // protect gx_s/gy_s + sred reuse
        int bb  = u / (K_*P_);
        int rem = u - bb*(K_*P_);
        int kk  = rem / P_;
        int pp  = rem - kk*P_;
        float kx = kps[((bb*P_ + pp)*K_ + kk)*2 + 0];
        float ky = kps[((bb*P_ + pp)*K_ + kk)*2 + 1];
        int   vv = vis[(bb*P_ + pp)*K_ + kk];
        float fx = floorf(kx * 191.f);   // row center
        float fy = floorf(ky * 191.f);   // col center
        bool ok = (vv > 0) && fx >= 0.f && fx < 192.f && fy >= 0.f && fy < 192.f;
        float acc = 0.f;
        if (ok) {
            int X0 = max(0, (int)fx - RADIUS), X1 = min(H_-1, (int)fx + RADIUS);
            int Y0 = max(0, (int)fy - RADIUS), Y1 = min(W_-1, (int)fy + RADIUS);
            int nr = X1 - X0 + 1, nc = Y1 - Y0 + 1;
            if (tid < nr) {
                float d = (float)(X0 + tid) - fx;
                gx_s[tid] = __expf(-d*d*inv18);
            } else if (tid >= 64 && tid - 64 < nc) {
                float d = (float)(Y0 + tid - 64) - fy;
                gy_s[tid - 64] = __expf(-d*d*inv18);
            }
            __syncthreads();
            const float* pb = s_pose + (size_t)(bb*K_ + kk) * HW_;
            int lim = nr << 6;
            for (int e = tid; e < lim; e += 256) {
                int row = e >> 6, col = e & 63;
                if (col < nc)
                    acc += pb[(X0 + row)*W_ + (Y0 + col)] * gx_s[row] * gy_s[col];
            }
        }
        acc = wave_red_sum(acc);
        if ((tid & 63) == 0) sred[tid >> 6][0] = acc;
        __syncthreads();
        if (tid == 0)
            ws[WS_STAMP + u] = sred[0][0] + sred[1][0] + sred[2][0] + sred[3][0];
    }

    // ---------------- phase 4: tsq closed form (blocks 0..543) ----------
    if (blk < TSQ_UNITS) {
        __syncthreads();
        int bb = blk / K_, kk = blk - bb*K_;
        int pq = tid >> 2, p = pq >> 3, q = pq & 7, ln = tid & 3;
        float kxp = kps[((bb*P_ + p)*K_ + kk)*2 + 0];
        float kyp = kps[((bb*P_ + p)*K_ + kk)*2 + 1];
        float kxq = kps[((bb*P_ + q)*K_ + kk)*2 + 0];
        float kyq = kps[((bb*P_ + q)*K_ + kk)*2 + 1];
        int vp = vis[(bb*P_ + p)*K_ + kk];
        int vq = vis[(bb*P_ + q)*K_ + kk];
        float axp = floorf(kxp * 191.f), ayp = floorf(kyp * 191.f);
        float axq = floorf(kxq * 191.f), ayq = floorf(kyq * 191.f);
        bool okp = (vp > 0) && axp >= 0.f && axp < 192.f && ayp >= 0.f && ayp < 192.f;
        bool okq = (vq > 0) && axq >= 0.f && axq < 192.f && ayq >= 0.f && ayq < 192.f;
        float sx = 0.f, sy = 0.f;
        int i0 = ln * 48;
        for (int i = i0; i < i0 + 48; i++) {
            float da = (float)i - axp, db = (float)i - axq;
            sx += __expf(-(da*da + db*db)*inv18);
            float ea = (float)i - ayp, eb = (float)i - ayq;
            sy += __expf(-(ea*ea + eb*eb)*inv18);
        }
        sx += __shfl_xor(sx, 1, 64); sy += __shfl_xor(sy, 1, 64);
        sx += __shfl_xor(sx, 2, 64); sy += __shfl_xor(sy, 2, 64);
        float val = (ln == 0 && okp && okq) ? sx * sy : 0.f;
        val = wave_red_sum(val);
        if ((tid & 63) == 0) sred[tid >> 6][0] = val;
        __syncthreads();
        if (tid == 0)
            ws[WS_TSQ + blk] = sred[0][0] + sred[1][0] + sred[2][0] + sred[3][0];
    }
}

// =====================================================================
// finalize: 1 block x 256 threads; 8 threads per batch row b.
//   mse_b = S2_b - 2*cross_b + tsq_b ;  KL_b = A/Zu + log(Zv) - log(Zu)
// =====================================================================
__global__ void __launch_bounds__(256) finalize_kernel(
        const float* __restrict__ ws, const int* __restrict__ vis,
        float* __restrict__ out) {
    __shared__ float rS2[B_][8], rZu[B_][8], rZv[B_][8], rA[B_][8];
    __shared__ float rCr[B_][8], rTq[B_][8];
    __shared__ int   rVs[B_][8];
    __shared__ float skl[B_], skp[B_];
    __shared__ float bw[4];
    int tid = threadIdx.x;
    int b = tid >> 3, s = tid & 7;

    float S2 = 0.f, Zu = 0.f, Zv = 0.f, A = 0.f, cr = 0.f, tq = 0.f;
    for (int j = s; j < PER_B_BLKS; j += 8) {
        const float* p = ws + WS_BLK + (size_t)(b*PER_B_BLKS + j) * 8;
        S2 += p[0]; Zu += p[1]; Zv += p[2]; A += p[3];
    }
    for (int j = s; j < K_*P_; j += 8) cr += ws[WS_STAMP + b*(K_*P_) + j];
    for (int j = s; j < K_;    j += 8) tq += ws[WS_TSQ + b*K_ + j];
    int vs = 0;
    for (int m = s; m < P_*K_; m += 8) vs += vis[b*(P_*K_) + m];
    rS2[b][s] = S2; rZu[b][s] = Zu; rZv[b][s] = Zv; rA[b][s] = A;
    rCr[b][s] = cr; rTq[b][s] = tq; rVs[b][s] = vs;

    float bce = 0.f;
    for (int i = tid; i < NBLKS; i += 256)
        bce += ws[WS_BLK + (size_t)i * 8 + 4];
    bce = wave_red_sum(bce);
    if ((tid & 63) == 0) bw[tid >> 6] = bce;
    __syncthreads();

    if (tid < B_) {
        float tS2=0.f, tZu=0.f, tZv=0.f, tA=0.f, tCr=0.f, tTq=0.f; int tVs=0;
#pragma unroll
        for (int q2 = 0; q2 < 8; q2++) {
            tS2 += rS2[tid][q2]; tZu += rZu[tid][q2]; tZv += rZv[tid][q2];
            tA  += rA[tid][q2];  tCr += rCr[tid][q2]; tTq += rTq[tid][q2];
            tVs += rVs[tid][q2];
        }
        float mse = tS2 - 2.f*tCr + tTq;
        skl[tid] = tA/tZu + (logf(tZv) - logf(tZu));
        skp[tid] = mse / ((float)tVs + 1e-6f);
    }
    __syncthreads();

    if (tid == 0) {
        float kl = 0.f, kpv = 0.f;
        for (int i = 0; i < B_; i++) { kl += skl[i]; kpv += skp[i]; }
        float bsum = bw[0] + bw[1] + bw[2] + bw[3];
        float pose_distill = 4.0f * kl / (float)B_;   // TEMP^2=4, batchmean
        float task_seg  = bsum / (float)(B_ * HW_);
        float task_pose = kpv / (float)B_;
        // seg_distill == 0 exactly (softmax over a size-1 channel axis)
        out[0] = 0.5f * pose_distill + 0.5f * (task_seg + task_pose);
    }
}

extern "C" void kernel_launch(void* const* d_in, const int* in_sizes, int n_in,
                              void* d_out, int out_size, void* d_ws, size_t ws_size,
                              hipStream_t stream) {
    const float* s_seg  = (const float*)d_in[0];
    const float* s_pose = (const float*)d_in[1];
    // d_in[2] (t_seg_logits) unused: seg_distill == 0 exactly
    const float* t_pose = (const float*)d_in[3];
    const float* mask   = (const float*)d_in[4];
    const float* kps    = (const float*)d_in[5];
    const int*   vis    = (const int*)d_in[6];
    float* out = (float*)d_out;
    float* ws  = (float*)d_ws;

    main_kernel<<<NBLKS, 256, 0, stream>>>(s_pose, t_pose, kps, vis,
                                           s_seg, mask, ws);
    finalize_kernel<<<1, 256, 0, stream>>>(ws, vis, out);
}

// Round 7
// 206.715 us; speedup vs baseline: 1.1034x; 1.0448x over previous
//
#include <hip/hip_runtime.h>
#include <math.h>

// Problem constants
#define B_   32
#define P_   8
#define K_   17
#define H_   192
#define W_   192
#define HW_  (H_*W_)              // 36864
#define PB4   156672              // K*H*W/4 float4 per batch row
#define NBLKS 2048                // 8 blocks/CU persistent
#define PER_B_BLKS 64             // blocks per batch row
#define CHUNK 16384               // 64 blocks * 256 threads (float4 stride)
#define FULL_IT 9                 // 9*16384 = 147456 of 156672
#define REM4  9216                // remainder float4 per b
#define BCE4  294912              // B*H*W/4

#define KPU  (K_*P_)              // 136 stamp units per batch row
#define TSQ_UNITS   (B_*K_)       // 544
#define RADIUS 18                 // exp(-18) ~ 1.5e-8: negligible tail

// ws layout (floats)
#define WS_BLK   0                // 2048*8: (S2,Zu,Zv,A,bce) per block
#define WS_STAMP 16384            // 4352: cross partial per (b,k,p)
#define WS_TSQ   20736            // 544: sum(t^2) per (b,k)

typedef __attribute__((ext_vector_type(4))) float f4v;

__device__ inline f4v ntload4(const float* p) {
    return __builtin_nontemporal_load((const f4v*)p);
}

__device__ inline float wave_red_sum(float v) {
    for (int o = 32; o; o >>= 1) v += __shfl_xor(v, o, 64);
    return v;
}

__device__ inline void kl_elem(float sv, float tv,
        float& S2, float& Zu, float& Zv, float& A) {
    S2 += sv*sv;
    float u = tv*0.5f, v = sv*0.5f;
    float eu = __expf(u);
    Zu += eu;
    A  += eu*(u - v);
    Zv += __expf(v);
}

// =====================================================================
// Persistent kernel, 2048 blocks x 256 thr. r7 changes vs r6:
//  (a) non-temporal loads on all big streams (probe: is the ~2.8 TB/s
//      logical wall a dirty-L2/L3 service-path artifact of the harness
//      restore? nt changes the cache path; everything else identical)
//  (b) stamp units assigned b-locally (block streams row b in phase 1,
//      then stamps within the same b -> L2-warm re-read)
// MSE = S2 - 2*cross + tsq; KL max-free (r5/r6-verified, absmax 0).
// =====================================================================
__global__ void __launch_bounds__(256) main_kernel(
        const float* __restrict__ s_pose, const float* __restrict__ t_pose,
        const float* __restrict__ kps,    const int* __restrict__ vis,
        const float* __restrict__ s_seg,  const float* __restrict__ mask,
        float* __restrict__ ws) {
    __shared__ float sred[4][5];
    __shared__ float gx_s[40], gy_s[40];

    const int blk = blockIdx.x;
    const int tid = threadIdx.x;
    const float inv18 = 1.0f / 18.0f;

    // ---------------- phase 1: pose stream (b-pinned) ----------------
    const int b  = blk >> 6;                     // 64 blocks per b
    const int lg = ((blk & 63) << 8) | tid;      // 0..16383 within b
    const float* s4 = s_pose + ((size_t)b*PB4 + lg)*4;
    const float* t4 = t_pose + ((size_t)b*PB4 + lg)*4;

    float S2 = 0.f, Zu = 0.f, Zv = 0.f, A = 0.f;
#pragma unroll 3
    for (int j = 0; j < FULL_IT; j++) {
        f4v sv = ntload4(s4 + (size_t)j*CHUNK*4);
        f4v tv = ntload4(t4 + (size_t)j*CHUNK*4);
        kl_elem(sv.x, tv.x, S2, Zu, Zv, A);
        kl_elem(sv.y, tv.y, S2, Zu, Zv, A);
        kl_elem(sv.z, tv.z, S2, Zu, Zv, A);
        kl_elem(sv.w, tv.w, S2, Zu, Zv, A);
    }
    if (lg < REM4) {
        f4v sv = ntload4(s4 + (size_t)FULL_IT*CHUNK*4);
        f4v tv = ntload4(t4 + (size_t)FULL_IT*CHUNK*4);
        kl_elem(sv.x, tv.x, S2, Zu, Zv, A);
        kl_elem(sv.y, tv.y, S2, Zu, Zv, A);
        kl_elem(sv.z, tv.z, S2, Zu, Zv, A);
        kl_elem(sv.w, tv.w, S2, Zu, Zv, A);
    }

    // ---------------- phase 2: BCE (one iter per thread) ----------------
    float bce = 0.f;
    {
        int gid = (blk << 8) | tid;
        if (gid < BCE4) {
            f4v xv = ntload4(s_seg + (size_t)gid*4);
            f4v mv = ntload4(mask  + (size_t)gid*4);
            bce += fmaxf(xv.x, 0.f) - xv.x*mv.x + log1pf(__expf(-fabsf(xv.x)));
            bce += fmaxf(xv.y, 0.f) - xv.y*mv.y + log1pf(__expf(-fabsf(xv.y)));
            bce += fmaxf(xv.z, 0.f) - xv.z*mv.z + log1pf(__expf(-fabsf(xv.z)));
            bce += fmaxf(xv.w, 0.f) - xv.w*mv.w + log1pf(__expf(-fabsf(xv.w)));
        }
    }

    // ---------------- single 5-value block reduction ----------------
    S2  = wave_red_sum(S2);
    Zu  = wave_red_sum(Zu);
    Zv  = wave_red_sum(Zv);
    A   = wave_red_sum(A);
    bce = wave_red_sum(bce);
    {
        int w = tid >> 6;
        if ((tid & 63) == 0) {
            sred[w][0] = S2; sred[w][1] = Zu; sred[w][2] = Zv;
            sred[w][3] = A;  sred[w][4] = bce;
        }
    }
    __syncthreads();
    if (tid == 0) {
        float* o = ws + WS_BLK + (size_t)blk * 8;
#pragma unroll
        for (int c = 0; c < 5; c++)
            o[c] = sred[0][c] + sred[1][c] + sred[2][c] + sred[3][c];
    }

    // -------- phase 3: cross-term stamps, b-local (L2-warm) ----------
    for (int j = blk & 63; j < KPU; j += 64) {
        __syncthreads();   // protect gx_s/gy_s + sred reuse
        int u   = b*KPU + j;
        int kk  = j / P_;
        int pp  = j - kk*P_;
        float kx = kps[((b*P_ + pp)*K_ + kk)*2 + 0];
        float ky = kps[((b*P_ + pp)*K_ + kk)*2 + 1];
        int   vv = vis[(b*P_ + pp)*K_ + kk];
        float fx = floorf(kx * 191.f);   // row center
        float fy = floorf(ky * 191.f);   // col center
        bool ok = (vv > 0) && fx >= 0.f && fx < 192.f && fy >= 0.f && fy < 192.f;
        float acc = 0.f;
        if (ok) {
            int X0 = max(0, (int)fx - RADIUS), X1 = min(H_-1, (int)fx + RADIUS);
            int Y0 = max(0, (int)fy - RADIUS), Y1 = min(W_-1, (int)fy + RADIUS);
            int nr = X1 - X0 + 1, nc = Y1 - Y0 + 1;
            if (tid < nr) {
                float d = (float)(X0 + tid) - fx;
                gx_s[tid] = __expf(-d*d*inv18);
            } else if (tid >= 64 && tid - 64 < nc) {
                float d = (float)(Y0 + tid - 64) - fy;
                gy_s[tid - 64] = __expf(-d*d*inv18);
            }
            __syncthreads();
            const float* pb = s_pose + (size_t)(b*K_ + kk) * HW_;
            int lim = nr << 6;
            for (int e = tid; e < lim; e += 256) {
                int row = e >> 6, col = e & 63;
                if (col < nc)
                    acc += pb[(X0 + row)*W_ + (Y0 + col)] * gx_s[row] * gy_s[col];
            }
        }
        acc = wave_red_sum(acc);
        if ((tid & 63) == 0) sred[tid >> 6][0] = acc;
        __syncthreads();
        if (tid == 0)
            ws[WS_STAMP + u] = sred[0][0] + sred[1][0] + sred[2][0] + sred[3][0];
    }

    // ---------------- phase 4: tsq closed form (blocks 0..543) ----------
    if (blk < TSQ_UNITS) {
        __syncthreads();
        int bb = blk / K_, kk = blk - bb*K_;
        int pq = tid >> 2, p = pq >> 3, q = pq & 7, ln = tid & 3;
        float kxp = kps[((bb*P_ + p)*K_ + kk)*2 + 0];
        float kyp = kps[((bb*P_ + p)*K_ + kk)*2 + 1];
        float kxq = kps[((bb*P_ + q)*K_ + kk)*2 + 0];
        float kyq = kps[((bb*P_ + q)*K_ + kk)*2 + 1];
        int vp = vis[(bb*P_ + p)*K_ + kk];
        int vq = vis[(bb*P_ + q)*K_ + kk];
        float axp = floorf(kxp * 191.f), ayp = floorf(kyp * 191.f);
        float axq = floorf(kxq * 191.f), ayq = floorf(kyq * 191.f);
        bool okp = (vp > 0) && axp >= 0.f && axp < 192.f && ayp >= 0.f && ayp < 192.f;
        bool okq = (vq > 0) && axq >= 0.f && axq < 192.f && ayq >= 0.f && ayq < 192.f;
        float sx = 0.f, sy = 0.f;
        int i0 = ln * 48;
        for (int i = i0; i < i0 + 48; i++) {
            float da = (float)i - axp, db = (float)i - axq;
            sx += __expf(-(da*da + db*db)*inv18);
            float ea = (float)i - ayp, eb = (float)i - ayq;
            sy += __expf(-(ea*ea + eb*eb)*inv18);
        }
        sx += __shfl_xor(sx, 1, 64); sy += __shfl_xor(sy, 1, 64);
        sx += __shfl_xor(sx, 2, 64); sy += __shfl_xor(sy, 2, 64);
        float val = (ln == 0 && okp && okq) ? sx * sy : 0.f;
        val = wave_red_sum(val);
        if ((tid & 63) == 0) sred[tid >> 6][0] = val;
        __syncthreads();
        if (tid == 0)
            ws[WS_TSQ + blk] = sred[0][0] + sred[1][0] + sred[2][0] + sred[3][0];
    }
}

// =====================================================================
// finalize: 1 block x 256 threads; 8 threads per batch row b.
//   mse_b = S2_b - 2*cross_b + tsq_b ;  KL_b = A/Zu + log(Zv) - log(Zu)
// =====================================================================
__global__ void __launch_bounds__(256) finalize_kernel(
        const float* __restrict__ ws, const int* __restrict__ vis,
        float* __restrict__ out) {
    __shared__ float rS2[B_][8], rZu[B_][8], rZv[B_][8], rA[B_][8];
    __shared__ float rCr[B_][8], rTq[B_][8];
    __shared__ int   rVs[B_][8];
    __shared__ float skl[B_], skp[B_];
    __shared__ float bw[4];
    int tid = threadIdx.x;
    int b = tid >> 3, s = tid & 7;

    float S2 = 0.f, Zu = 0.f, Zv = 0.f, A = 0.f, cr = 0.f, tq = 0.f;
    for (int j = s; j < PER_B_BLKS; j += 8) {
        const float* p = ws + WS_BLK + (size_t)(b*PER_B_BLKS + j) * 8;
        S2 += p[0]; Zu += p[1]; Zv += p[2]; A += p[3];
    }
    for (int j = s; j < KPU; j += 8) cr += ws[WS_STAMP + b*KPU + j];
    for (int j = s; j < K_;  j += 8) tq += ws[WS_TSQ + b*K_ + j];
    int vs = 0;
    for (int m = s; m < P_*K_; m += 8) vs += vis[b*(P_*K_) + m];
    rS2[b][s] = S2; rZu[b][s] = Zu; rZv[b][s] = Zv; rA[b][s] = A;
    rCr[b][s] = cr; rTq[b][s] = tq; rVs[b][s] = vs;

    float bce = 0.f;
    for (int i = tid; i < NBLKS; i += 256)
        bce += ws[WS_BLK + (size_t)i * 8 + 4];
    bce = wave_red_sum(bce);
    if ((tid & 63) == 0) bw[tid >> 6] = bce;
    __syncthreads();

    if (tid < B_) {
        float tS2=0.f, tZu=0.f, tZv=0.f, tA=0.f, tCr=0.f, tTq=0.f; int tVs=0;
#pragma unroll
        for (int q2 = 0; q2 < 8; q2++) {
            tS2 += rS2[tid][q2]; tZu += rZu[tid][q2]; tZv += rZv[tid][q2];
            tA  += rA[tid][q2];  tCr += rCr[tid][q2]; tTq += rTq[tid][q2];
            tVs += rVs[tid][q2];
        }
        float mse = tS2 - 2.f*tCr + tTq;
        skl[tid] = tA/tZu + (logf(tZv) - logf(tZu));
        skp[tid] = mse / ((float)tVs + 1e-6f);
    }
    __syncthreads();

    if (tid == 0) {
        float kl = 0.f, kpv = 0.f;
        for (int i = 0; i < B_; i++) { kl += skl[i]; kpv += skp[i]; }
        float bsum = bw[0] + bw[1] + bw[2] + bw[3];
        float pose_distill = 4.0f * kl / (float)B_;   // TEMP^2=4, batchmean
        float task_seg  = bsum / (float)(B_ * HW_);
        float task_pose = kpv / (float)B_;
        // seg_distill == 0 exactly (softmax over a size-1 channel axis)
        out[0] = 0.5f * pose_distill + 0.5f * (task_seg + task_pose);
    }
}

extern "C" void kernel_launch(void* const* d_in, const int* in_sizes, int n_in,
                              void* d_out, int out_size, void* d_ws, size_t ws_size,
                              hipStream_t stream) {
    const float* s_seg  = (const float*)d_in[0];
    const float* s_pose = (const float*)d_in[1];
    // d_in[2] (t_seg_logits) unused: seg_distill == 0 exactly
    const float* t_pose = (const float*)d_in[3];
    const float* mask   = (const float*)d_in[4];
    const float* kps    = (const float*)d_in[5];
    const int*   vis    = (const int*)d_in[6];
    float* out = (float*)d_out;
    float* ws  = (float*)d_ws;

    main_kernel<<<NBLKS, 256, 0, stream>>>(s_pose, t_pose, kps, vis,
                                           s_seg, mask, ws);
    finalize_kernel<<<1, 256, 0, stream>>>(ws, vis, out);
}